// Round 7
// baseline (3003.582 us; speedup 1.0000x reference)
//
#include <hip/hip_runtime.h>
#include <math.h>

#define M_ROWS 2048
#define N_COLS 2048
#define DIMS 512
#define IN_STRIDE 513
#define DP_BLOCKS 32
#define DP_COLS 64

constexpr float GAMMA = 0.001f;
constexpr float LOG2E = 1.44269504088896f;
constexpr float LN2   = 0.69314718055995f;

// hardware base-2 exp/log (v_exp_f32 / v_log_f32). NOTE: __exp2f/__log2f collide
// with glibc math.h internals on this toolchain — use the amdgcn builtins.
__device__ __forceinline__ float fexp2(float x) { return __builtin_amdgcn_exp2f(x); }
__device__ __forceinline__ float flog2(float x) { return __builtin_amdgcn_logf(x); }

// ---------------- argsort by timestamp (last column), stable ----------------
__global__ void argsort_kernel(const float* __restrict__ a, const float* __restrict__ b,
                               int* __restrict__ permA, int* __restrict__ permB) {
    const float* src = blockIdx.y ? b : a;
    int* perm = blockIdx.y ? permB : permA;
    __shared__ float keys[M_ROWS];
    for (int j = threadIdx.x; j < M_ROWS; j += blockDim.x)
        keys[j] = src[(size_t)j * IN_STRIDE + DIMS];
    __syncthreads();
    int i = blockIdx.x * blockDim.x + threadIdx.x;
    float ki = keys[i];
    int rank = 0;
    for (int j = 0; j < M_ROWS; ++j) {
        float kj = keys[j];
        rank += (kj < ki) || (kj == ki && j < i);  // stable rank
    }
    perm[rank] = i;
}

// ---------------- gather sorted rows + L2-normalize (drop time col) ----------------
__global__ __launch_bounds__(128) void norm_kernel(const float* __restrict__ a, const float* __restrict__ b,
                                                   const int* __restrict__ permA, const int* __restrict__ permB,
                                                   float* __restrict__ Ahat, float* __restrict__ Bhat) {
    const float* src = blockIdx.y ? b : a;
    const int* perm = blockIdx.y ? permB : permA;
    float* dst = blockIdx.y ? Bhat : Ahat;
    int r = blockIdx.x;
    int row = perm[r];
    const float* p = src + (size_t)row * IN_STRIDE;
    int tid = threadIdx.x;
    float v0 = p[tid], v1 = p[tid + 128], v2 = p[tid + 256], v3 = p[tid + 384];
    float ss = v0 * v0 + v1 * v1 + v2 * v2 + v3 * v3;
    #pragma unroll
    for (int off = 32; off > 0; off >>= 1) ss += __shfl_down(ss, off);
    __shared__ float red[2];
    if ((tid & 63) == 0) red[tid >> 6] = ss;
    __syncthreads();
    float inv = 1.0f / sqrtf(red[0] + red[1] + 1e-10f);
    float* q = dst + (size_t)r * DIMS;
    q[tid] = v0 * inv; q[tid + 128] = v1 * inv; q[tid + 256] = v2 * inv; q[tid + 384] = v3 * inv;
}

// ---------------- GEMM: Q[i][n] = exp(-1 - dot(Ahat[i], Bhat[n])) = exp(cost-2) ----------------
__global__ __launch_bounds__(256) void gemm_kernel(const float* __restrict__ A, const float* __restrict__ B,
                                                   float* __restrict__ Q) {
    __shared__ float As[16][68];
    __shared__ float Bs[16][68];
    int tid = threadIdx.x;
    int tx = tid & 15, ty = tid >> 4;
    int row0 = blockIdx.y * 64;
    int col0 = blockIdx.x * 64;
    int lrow = tid >> 2;          // 0..63
    int lk = (tid & 3) * 4;       // 0,4,8,12
    const float* ap = A + (size_t)(row0 + lrow) * DIMS + lk;
    const float* bp = B + (size_t)(col0 + lrow) * DIMS + lk;
    float acc[4][4] = {};
    for (int k0 = 0; k0 < DIMS; k0 += 16) {
        float4 av = *(const float4*)ap; ap += 16;
        float4 bv = *(const float4*)bp; bp += 16;
        __syncthreads();
        As[lk + 0][lrow] = av.x; As[lk + 1][lrow] = av.y; As[lk + 2][lrow] = av.z; As[lk + 3][lrow] = av.w;
        Bs[lk + 0][lrow] = bv.x; Bs[lk + 1][lrow] = bv.y; Bs[lk + 2][lrow] = bv.z; Bs[lk + 3][lrow] = bv.w;
        __syncthreads();
        #pragma unroll
        for (int k = 0; k < 16; ++k) {
            float4 a4 = *(const float4*)&As[k][ty * 4];
            float4 b4 = *(const float4*)&Bs[k][tx * 4];
            float aa[4] = {a4.x, a4.y, a4.z, a4.w};
            float bb[4] = {b4.x, b4.y, b4.z, b4.w};
            #pragma unroll
            for (int u = 0; u < 4; ++u)
                #pragma unroll
                for (int v = 0; v < 4; ++v)
                    acc[u][v] += aa[u] * bb[v];
        }
    }
    #pragma unroll
    for (int u = 0; u < 4; ++u) {
        float4 o;
        o.x = __expf(-1.0f - acc[u][0]);
        o.y = __expf(-1.0f - acc[u][1]);
        o.z = __expf(-1.0f - acc[u][2]);
        o.w = __expf(-1.0f - acc[u][3]);
        *(float4*)&Q[(size_t)(row0 + ty * 4 + u) * N_COLS + col0 + tx * 4] = o;
    }
}

// ---------------- per-row softmax denom -> rs2 = log2e/(gamma*denom) ----------------
// log2 We = -rs2 ; log2 Wo[n] = -rs2*Q[n]
__global__ __launch_bounds__(256) void rowstat_kernel(const float* __restrict__ Q,
                                                      float* __restrict__ rowscale) {
    int i = blockIdx.x;
    const float* q = Q + (size_t)i * N_COLS;
    int tid = threadIdx.x;
    float4 x = *(const float4*)(q + tid * 4);
    float4 y = *(const float4*)(q + 1024 + tid * 4);
    float s = x.x + x.y + x.z + x.w + y.x + y.y + y.z + y.w;
    #pragma unroll
    for (int off = 32; off > 0; off >>= 1) s += __shfl_down(s, off);
    __shared__ float red[4];
    if ((tid & 63) == 0) red[tid >> 6] = s;
    __syncthreads();
    if (tid == 0) {
        float denom = 2049.0f + red[0] + red[1] + red[2] + red[3];
        rowscale[i] = (LOG2E / GAMMA) / denom;
    }
}

// ---------------- (m,s) pair arithmetic: value = m + log2(s) ----------------
struct Pair { float m, s; };

// combine two pairs (log-sum-exp in base 2); one transcendental, no log
__device__ __forceinline__ Pair pcomb(Pair a, Pair b) {
    float e = fexp2(-fabsf(a.m - b.m));
    bool c = a.m >= b.m;
    Pair r;
    r.m = c ? a.m : b.m;
    r.s = c ? fmaf(b.s, e, a.s) : fmaf(a.s, e, b.s);
    return r;
}
// exact renormalization: pull s's exponent into m (s -> [1,2)), integer ops only
__device__ __forceinline__ void renorm(float& m, float& s) {
    int bits = __float_as_int(s);
    int ex = ((bits >> 23) & 255) - 127;
    m += (float)ex;
    s = __int_as_float(bits - (ex << 23));
}

// ---------------- pipelined multi-block DP: 32 blocks x 1 wave, 1 column/lane ----
// Block b owns P-columns [64b, 64b+64). Per row i:
//   g[lane] = {mP + LG2_i[col], sP}            (LG2 computed from Q one row ahead)
//   wave-inclusive pair-scan of g (6 shfl steps, no LDS, no barrier)
//   carry_in = inclusive prefix through col 64b-1  (from block b-1, packed u64 atomic)
//   P_new = (carry_in (+) excl_scan) (+) {mP + lwe, sP};   carry_out = carry_in (+) total
// Block 31 additionally folds h (column 4096): h_new = carry_out (+) {mH+lwe, sH}.
// Packed carry: hi=s bits (s>=1 => nonzero), lo=m bits; 0 == "not ready" (memset).
// Producer: atomicExch (device-scope). Consumer: atomicAdd(ptr,0) poll; first attempt
// issued BEFORE the scan so its latency overlaps the scan chain.
__global__ __launch_bounds__(64) void dp_kernel(const float* __restrict__ Q,
                                                const float* __restrict__ Rs,
                                                unsigned long long* __restrict__ carry,
                                                float* __restrict__ out) {
    const int b = blockIdx.x;
    const int lane = threadIdx.x;
    const float* qcol = Q + b * DP_COLS + lane;

    float mP = 0.f, sP = 1.f;      // virtual row -1: P = log2(1)
    float mH = 0.f, sH = 1.f;      // block 31 only

    // 4-deep prefetch ring for Q column values and row scales
    float qr[4], rr[4];
    #pragma unroll
    for (int k = 0; k < 4; ++k) {
        qr[k] = qcol[(size_t)k * N_COLS];
        rr[k] = Rs[k];
    }
    float rs0 = rr[0];
    float lg_cur = flog2(fexp2(-rs0) + fexp2(-rs0 * qr[0]));
    float lwe_cur = -rs0;

    for (int i = 0; i < M_ROWS; ++i) {
        // early poll attempt (overlaps the scan below)
        unsigned long long pk = 1ull;
        unsigned long long* src = carry + (size_t)i * DP_BLOCKS + (b - 1);
        if (b > 0) pk = atomicAdd(src, 0ull);

        // g and wave-inclusive pair scan
        Pair v{mP + lg_cur, sP};
        #pragma unroll
        for (int off = 1; off < 64; off <<= 1) {
            float pm = __shfl_up(v.m, off);
            float ps = __shfl_up(v.s, off);
            if (lane >= off) v = pcomb(v, Pair{pm, ps});
        }
        float em = __shfl_up(v.m, 1), es = __shfl_up(v.s, 1);
        Pair excl = (lane == 0) ? Pair{-1e30f, 0.f} : Pair{em, es};

        // off-chain: LG2 for row i+1 from ring (data loaded >=3 iters ago)
        float lg_nxt, lwe_nxt;
        {
            int k1 = (i + 1) & 3;
            float rs1 = rr[k1];
            lg_nxt = flog2(fexp2(-rs1) + fexp2(-rs1 * qr[k1]));
            lwe_nxt = -rs1;
        }

        // finish carry poll
        Pair cin{-1e30f, 0.f};
        if (b > 0) {
            while (pk == 0ull) pk = atomicAdd(src, 0ull);
            cin.m = __uint_as_float((unsigned)(pk & 0xFFFFFFFFull));
            cin.s = __uint_as_float((unsigned)(pk >> 32));
        }

        // carry out = cin (+) total  (total broadcast from lane 63)
        Pair incl63{__shfl(v.m, 63), __shfl(v.s, 63)};
        Pair tot = pcomb(cin, incl63);
        if (b < DP_BLOCKS - 1) {
            if (lane == 63) {
                unsigned long long po = ((unsigned long long)__float_as_uint(tot.s) << 32) |
                                        (unsigned long long)__float_as_uint(tot.m);
                atomicExch(carry + (size_t)i * DP_BLOCKS + b, po);
            }
        } else {
            Pair hh = pcomb(tot, Pair{mH + lwe_cur, sH});
            mH = hh.m; sH = hh.s;
            renorm(mH, sH);
        }

        // P update
        Pair base = pcomb(cin, excl);
        Pair np = pcomb(base, Pair{mP + lwe_cur, sP});
        mP = np.m; sP = np.s;
        renorm(mP, sP);

        // rotate prefetch ring (row i+4)
        int k4 = i & 3;
        if (i + 4 < M_ROWS) {
            qr[k4] = qcol[(size_t)(i + 4) * N_COLS];
            rr[k4] = Rs[i + 4];
        }
        lg_cur = lg_nxt; lwe_cur = lwe_nxt;
    }
    if (b == DP_BLOCKS - 1 && lane == 0)
        out[0] = -GAMMA * LN2 * (mH + flog2(sH));
}

extern "C" void kernel_launch(void* const* d_in, const int* in_sizes, int n_in,
                              void* d_out, int out_size, void* d_ws, size_t ws_size,
                              hipStream_t stream) {
    (void)in_sizes; (void)n_in; (void)out_size; (void)ws_size;
    const float* a = (const float*)d_in[0];
    const float* b = (const float*)d_in[1];
    float* out = (float*)d_out;
    char* ws = (char*)d_ws;
    float* Q        = (float*)(ws);                                    // 16 MB
    float* Ahat     = (float*)(ws + (size_t)16 * 1024 * 1024);         // 4 MB
    float* Bhat     = (float*)(ws + (size_t)20 * 1024 * 1024);         // 4 MB
    float* rowscale = (float*)(ws + (size_t)24 * 1024 * 1024);         // 8 KB
    int* permA      = (int*)(ws + (size_t)24 * 1024 * 1024 + 8192);    // 8 KB
    int* permB      = (int*)(ws + (size_t)24 * 1024 * 1024 + 16384);   // 8 KB
    unsigned long long* carry = (unsigned long long*)(ws + (size_t)25 * 1024 * 1024); // 512 KB

    hipMemsetAsync(carry, 0, (size_t)M_ROWS * DP_BLOCKS * sizeof(unsigned long long), stream);
    argsort_kernel<<<dim3(8, 2), 256, 0, stream>>>(a, b, permA, permB);
    norm_kernel<<<dim3(2048, 2), 128, 0, stream>>>(a, b, permA, permB, Ahat, Bhat);
    gemm_kernel<<<dim3(32, 32), 256, 0, stream>>>(Ahat, Bhat, Q);
    rowstat_kernel<<<2048, 256, 0, stream>>>(Q, rowscale);
    dp_kernel<<<DP_BLOCKS, DP_COLS, 0, stream>>>(Q, rowscale, carry, out);
}

// Round 8
// 2096.126 us; speedup vs baseline: 1.4329x; 1.4329x over previous
//
#include <hip/hip_runtime.h>
#include <math.h>

#define M_ROWS 2048
#define N_COLS 2048
#define DIMS 512
#define IN_STRIDE 513
#define DP_BLOCKS 32
#define DP_COLS 64

constexpr float GAMMA = 0.001f;
constexpr float LOG2E = 1.44269504088896f;
constexpr float LN2   = 0.69314718055995f;

// hardware base-2 exp/log (v_exp_f32 / v_log_f32). NOTE: __exp2f/__log2f collide
// with glibc math.h internals on this toolchain — use the amdgcn builtins.
__device__ __forceinline__ float fexp2(float x) { return __builtin_amdgcn_exp2f(x); }
__device__ __forceinline__ float flog2(float x) { return __builtin_amdgcn_logf(x); }

// ---------------- argsort by timestamp (last column), stable ----------------
__global__ void argsort_kernel(const float* __restrict__ a, const float* __restrict__ b,
                               int* __restrict__ permA, int* __restrict__ permB) {
    const float* src = blockIdx.y ? b : a;
    int* perm = blockIdx.y ? permB : permA;
    __shared__ float keys[M_ROWS];
    for (int j = threadIdx.x; j < M_ROWS; j += blockDim.x)
        keys[j] = src[(size_t)j * IN_STRIDE + DIMS];
    __syncthreads();
    int i = blockIdx.x * blockDim.x + threadIdx.x;
    float ki = keys[i];
    int rank = 0;
    for (int j = 0; j < M_ROWS; ++j) {
        float kj = keys[j];
        rank += (kj < ki) || (kj == ki && j < i);  // stable rank
    }
    perm[rank] = i;
}

// ---------------- gather sorted rows + L2-normalize (drop time col) ----------------
__global__ __launch_bounds__(128) void norm_kernel(const float* __restrict__ a, const float* __restrict__ b,
                                                   const int* __restrict__ permA, const int* __restrict__ permB,
                                                   float* __restrict__ Ahat, float* __restrict__ Bhat) {
    const float* src = blockIdx.y ? b : a;
    const int* perm = blockIdx.y ? permB : permA;
    float* dst = blockIdx.y ? Bhat : Ahat;
    int r = blockIdx.x;
    int row = perm[r];
    const float* p = src + (size_t)row * IN_STRIDE;
    int tid = threadIdx.x;
    float v0 = p[tid], v1 = p[tid + 128], v2 = p[tid + 256], v3 = p[tid + 384];
    float ss = v0 * v0 + v1 * v1 + v2 * v2 + v3 * v3;
    #pragma unroll
    for (int off = 32; off > 0; off >>= 1) ss += __shfl_down(ss, off);
    __shared__ float red[2];
    if ((tid & 63) == 0) red[tid >> 6] = ss;
    __syncthreads();
    float inv = 1.0f / sqrtf(red[0] + red[1] + 1e-10f);
    float* q = dst + (size_t)r * DIMS;
    q[tid] = v0 * inv; q[tid + 128] = v1 * inv; q[tid + 256] = v2 * inv; q[tid + 384] = v3 * inv;
}

// ---------------- GEMM: Q[i][n] = exp(-1 - dot(Ahat[i], Bhat[n])) = exp(cost-2) ----------------
__global__ __launch_bounds__(256) void gemm_kernel(const float* __restrict__ A, const float* __restrict__ B,
                                                   float* __restrict__ Q) {
    __shared__ float As[16][68];
    __shared__ float Bs[16][68];
    int tid = threadIdx.x;
    int tx = tid & 15, ty = tid >> 4;
    int row0 = blockIdx.y * 64;
    int col0 = blockIdx.x * 64;
    int lrow = tid >> 2;          // 0..63
    int lk = (tid & 3) * 4;       // 0,4,8,12
    const float* ap = A + (size_t)(row0 + lrow) * DIMS + lk;
    const float* bp = B + (size_t)(col0 + lrow) * DIMS + lk;
    float acc[4][4] = {};
    for (int k0 = 0; k0 < DIMS; k0 += 16) {
        float4 av = *(const float4*)ap; ap += 16;
        float4 bv = *(const float4*)bp; bp += 16;
        __syncthreads();
        As[lk + 0][lrow] = av.x; As[lk + 1][lrow] = av.y; As[lk + 2][lrow] = av.z; As[lk + 3][lrow] = av.w;
        Bs[lk + 0][lrow] = bv.x; Bs[lk + 1][lrow] = bv.y; Bs[lk + 2][lrow] = bv.z; Bs[lk + 3][lrow] = bv.w;
        __syncthreads();
        #pragma unroll
        for (int k = 0; k < 16; ++k) {
            float4 a4 = *(const float4*)&As[k][ty * 4];
            float4 b4 = *(const float4*)&Bs[k][tx * 4];
            float aa[4] = {a4.x, a4.y, a4.z, a4.w};
            float bb[4] = {b4.x, b4.y, b4.z, b4.w};
            #pragma unroll
            for (int u = 0; u < 4; ++u)
                #pragma unroll
                for (int v = 0; v < 4; ++v)
                    acc[u][v] += aa[u] * bb[v];
        }
    }
    #pragma unroll
    for (int u = 0; u < 4; ++u) {
        float4 o;
        o.x = __expf(-1.0f - acc[u][0]);
        o.y = __expf(-1.0f - acc[u][1]);
        o.z = __expf(-1.0f - acc[u][2]);
        o.w = __expf(-1.0f - acc[u][3]);
        *(float4*)&Q[(size_t)(row0 + ty * 4 + u) * N_COLS + col0 + tx * 4] = o;
    }
}

// ---------------- per-row softmax denom -> rs2 = log2e/(gamma*denom) ----------------
// log2 We = -rs2 ; log2 Wo[n] = -rs2*Q[n]
__global__ __launch_bounds__(256) void rowstat_kernel(const float* __restrict__ Q,
                                                      float* __restrict__ rowscale) {
    int i = blockIdx.x;
    const float* q = Q + (size_t)i * N_COLS;
    int tid = threadIdx.x;
    float4 x = *(const float4*)(q + tid * 4);
    float4 y = *(const float4*)(q + 1024 + tid * 4);
    float s = x.x + x.y + x.z + x.w + y.x + y.y + y.z + y.w;
    #pragma unroll
    for (int off = 32; off > 0; off >>= 1) s += __shfl_down(s, off);
    __shared__ float red[4];
    if ((tid & 63) == 0) red[tid >> 6] = s;
    __syncthreads();
    if (tid == 0) {
        float denom = 2049.0f + red[0] + red[1] + red[2] + red[3];
        rowscale[i] = (LOG2E / GAMMA) / denom;
    }
}

// ---------------- (m,s) pair arithmetic: value = m + log2(s) ----------------
struct Pair { float m, s; };

// combine two pairs (log-sum-exp in base 2); one transcendental, no log
__device__ __forceinline__ Pair pcomb(Pair a, Pair b) {
    float e = fexp2(-fabsf(a.m - b.m));
    bool c = a.m >= b.m;
    Pair r;
    r.m = c ? a.m : b.m;
    r.s = c ? fmaf(b.s, e, a.s) : fmaf(a.s, e, b.s);
    return r;
}
// exact renormalization: pull s's exponent into m (s -> [1,2)), integer ops only
__device__ __forceinline__ void renorm(float& m, float& s) {
    int bits = __float_as_int(s);
    int ex = ((bits >> 23) & 255) - 127;
    m += (float)ex;
    s = __int_as_float(bits - (ex << 23));
}

// ---------------- pipelined multi-block DP: 32 blocks x 1 wave, 1 column/lane ----
// Block b owns P-columns [64b, 64b+64). Per row i:
//   g[lane] = {mP + LG2_i[col], sP}            (LG2 computed from Q one row ahead)
//   wave-inclusive pair-scan of g (6 shfl steps, no LDS, no barrier)
//   carry_in = inclusive prefix through col 64b-1  (from block b-1, packed u64)
//   P_new = (carry_in (+) excl_scan) (+) {mP + lwe, sP};   carry_out = carry_in (+) total
// Block 31 additionally folds h (column 4096): h_new = carry_out (+) {mH+lwe, sH}.
// Packed carry: hi=s bits (s>=1 => nonzero), lo=m bits; 0 == "not ready" (memset).
// Producer: single-lane atomicExch. Consumer: LANE-0-ONLY scoped atomic LOAD
// (no RMW serialization — round 7's all-lane atomicAdd poll cost ~2900 cy/row),
// result broadcast to the wave via two shfls. First poll issued BEFORE the scan.
__global__ __launch_bounds__(64) void dp_kernel(const float* __restrict__ Q,
                                                const float* __restrict__ Rs,
                                                unsigned long long* __restrict__ carry,
                                                float* __restrict__ out) {
    const int b = blockIdx.x;
    const int lane = threadIdx.x;
    const float* qcol = Q + b * DP_COLS + lane;

    float mP = 0.f, sP = 1.f;      // virtual row -1: P = log2(1)
    float mH = 0.f, sH = 1.f;      // block 31 only

    // 4-deep prefetch ring for Q column values and row scales
    float qr[4], rr[4];
    #pragma unroll
    for (int k = 0; k < 4; ++k) {
        qr[k] = qcol[(size_t)k * N_COLS];
        rr[k] = Rs[k];
    }
    float rs0 = rr[0];
    float lg_cur = flog2(fexp2(-rs0) + fexp2(-rs0 * qr[0]));
    float lwe_cur = -rs0;

    for (int i = 0; i < M_ROWS; ++i) {
        // early poll attempt (lane 0 only; overlaps the scan below)
        unsigned long long pk = 1ull;
        const unsigned long long* src = carry + (size_t)i * DP_BLOCKS + (b - 1);
        if (b > 0 && lane == 0)
            pk = __hip_atomic_load(src, __ATOMIC_RELAXED, __HIP_MEMORY_SCOPE_AGENT);

        // g and wave-inclusive pair scan
        Pair v{mP + lg_cur, sP};
        #pragma unroll
        for (int off = 1; off < 64; off <<= 1) {
            float pm = __shfl_up(v.m, off);
            float ps = __shfl_up(v.s, off);
            if (lane >= off) v = pcomb(v, Pair{pm, ps});
        }
        float em = __shfl_up(v.m, 1), es = __shfl_up(v.s, 1);
        Pair excl = (lane == 0) ? Pair{-1e30f, 0.f} : Pair{em, es};

        // off-chain: LG2 for row i+1 from ring (data loaded >=3 iters ago)
        float lg_nxt, lwe_nxt;
        {
            int k1 = (i + 1) & 3;
            float rs1 = rr[k1];
            lg_nxt = flog2(fexp2(-rs1) + fexp2(-rs1 * qr[k1]));
            lwe_nxt = -rs1;
        }

        // finish carry poll (lane 0 spins on a plain coherent load), broadcast
        Pair cin{-1e30f, 0.f};
        if (b > 0) {
            if (lane == 0) {
                while (pk == 0ull)
                    pk = __hip_atomic_load(src, __ATOMIC_RELAXED, __HIP_MEMORY_SCOPE_AGENT);
            }
            unsigned lo = (unsigned)__shfl((int)(unsigned)(pk & 0xFFFFFFFFull), 0);
            unsigned hi = (unsigned)__shfl((int)(unsigned)(pk >> 32), 0);
            cin.m = __uint_as_float(lo);
            cin.s = __uint_as_float(hi);
        }

        // carry out = cin (+) total  (total broadcast from lane 63)
        Pair incl63{__shfl(v.m, 63), __shfl(v.s, 63)};
        Pair tot = pcomb(cin, incl63);
        if (b < DP_BLOCKS - 1) {
            if (lane == 63) {
                unsigned long long po = ((unsigned long long)__float_as_uint(tot.s) << 32) |
                                        (unsigned long long)__float_as_uint(tot.m);
                atomicExch(carry + (size_t)i * DP_BLOCKS + b, po);
            }
        } else {
            Pair hh = pcomb(tot, Pair{mH + lwe_cur, sH});
            mH = hh.m; sH = hh.s;
            renorm(mH, sH);
        }

        // P update
        Pair base = pcomb(cin, excl);
        Pair np = pcomb(base, Pair{mP + lwe_cur, sP});
        mP = np.m; sP = np.s;
        renorm(mP, sP);

        // rotate prefetch ring (row i+4)
        int k4 = i & 3;
        if (i + 4 < M_ROWS) {
            qr[k4] = qcol[(size_t)(i + 4) * N_COLS];
            rr[k4] = Rs[i + 4];
        }
        lg_cur = lg_nxt; lwe_cur = lwe_nxt;
    }
    if (b == DP_BLOCKS - 1 && lane == 0)
        out[0] = -GAMMA * LN2 * (mH + flog2(sH));
}

extern "C" void kernel_launch(void* const* d_in, const int* in_sizes, int n_in,
                              void* d_out, int out_size, void* d_ws, size_t ws_size,
                              hipStream_t stream) {
    (void)in_sizes; (void)n_in; (void)out_size; (void)ws_size;
    const float* a = (const float*)d_in[0];
    const float* b = (const float*)d_in[1];
    float* out = (float*)d_out;
    char* ws = (char*)d_ws;
    float* Q        = (float*)(ws);                                    // 16 MB
    float* Ahat     = (float*)(ws + (size_t)16 * 1024 * 1024);         // 4 MB
    float* Bhat     = (float*)(ws + (size_t)20 * 1024 * 1024);         // 4 MB
    float* rowscale = (float*)(ws + (size_t)24 * 1024 * 1024);         // 8 KB
    int* permA      = (int*)(ws + (size_t)24 * 1024 * 1024 + 8192);    // 8 KB
    int* permB      = (int*)(ws + (size_t)24 * 1024 * 1024 + 16384);   // 8 KB
    unsigned long long* carry = (unsigned long long*)(ws + (size_t)25 * 1024 * 1024); // 512 KB

    hipMemsetAsync(carry, 0, (size_t)M_ROWS * DP_BLOCKS * sizeof(unsigned long long), stream);
    argsort_kernel<<<dim3(8, 2), 256, 0, stream>>>(a, b, permA, permB);
    norm_kernel<<<dim3(2048, 2), 128, 0, stream>>>(a, b, permA, permB, Ahat, Bhat);
    gemm_kernel<<<dim3(32, 32), 256, 0, stream>>>(Ahat, Bhat, Q);
    rowstat_kernel<<<2048, 256, 0, stream>>>(Q, rowscale);
    dp_kernel<<<DP_BLOCKS, DP_COLS, 0, stream>>>(Q, rowscale, carry, out);
}

// Round 9
// 1996.852 us; speedup vs baseline: 1.5042x; 1.0497x over previous
//
#include <hip/hip_runtime.h>
#include <math.h>

#define M_ROWS 2048
#define N_COLS 2048
#define DIMS 512
#define IN_STRIDE 513
#define DP_BLOCKS 32
#define DP_COLS 64

constexpr float GAMMA = 0.001f;
constexpr float LOG2E = 1.44269504088896f;
constexpr float LN2   = 0.69314718055995f;

// hardware base-2 exp/log (v_exp_f32 / v_log_f32). NOTE: __exp2f/__log2f collide
// with glibc math.h internals on this toolchain — use the amdgcn builtins.
__device__ __forceinline__ float fexp2(float x) { return __builtin_amdgcn_exp2f(x); }
__device__ __forceinline__ float flog2(float x) { return __builtin_amdgcn_logf(x); }

// ---------------- argsort by timestamp (last column), stable ----------------
__global__ void argsort_kernel(const float* __restrict__ a, const float* __restrict__ b,
                               int* __restrict__ permA, int* __restrict__ permB) {
    const float* src = blockIdx.y ? b : a;
    int* perm = blockIdx.y ? permB : permA;
    __shared__ float keys[M_ROWS];
    for (int j = threadIdx.x; j < M_ROWS; j += blockDim.x)
        keys[j] = src[(size_t)j * IN_STRIDE + DIMS];
    __syncthreads();
    int i = blockIdx.x * blockDim.x + threadIdx.x;
    float ki = keys[i];
    int rank = 0;
    for (int j = 0; j < M_ROWS; ++j) {
        float kj = keys[j];
        rank += (kj < ki) || (kj == ki && j < i);  // stable rank
    }
    perm[rank] = i;
}

// ---------------- gather sorted rows + L2-normalize (drop time col) ----------------
__global__ __launch_bounds__(128) void norm_kernel(const float* __restrict__ a, const float* __restrict__ b,
                                                   const int* __restrict__ permA, const int* __restrict__ permB,
                                                   float* __restrict__ Ahat, float* __restrict__ Bhat) {
    const float* src = blockIdx.y ? b : a;
    const int* perm = blockIdx.y ? permB : permA;
    float* dst = blockIdx.y ? Bhat : Ahat;
    int r = blockIdx.x;
    int row = perm[r];
    const float* p = src + (size_t)row * IN_STRIDE;
    int tid = threadIdx.x;
    float v0 = p[tid], v1 = p[tid + 128], v2 = p[tid + 256], v3 = p[tid + 384];
    float ss = v0 * v0 + v1 * v1 + v2 * v2 + v3 * v3;
    #pragma unroll
    for (int off = 32; off > 0; off >>= 1) ss += __shfl_down(ss, off);
    __shared__ float red[2];
    if ((tid & 63) == 0) red[tid >> 6] = ss;
    __syncthreads();
    float inv = 1.0f / sqrtf(red[0] + red[1] + 1e-10f);
    float* q = dst + (size_t)r * DIMS;
    q[tid] = v0 * inv; q[tid + 128] = v1 * inv; q[tid + 256] = v2 * inv; q[tid + 384] = v3 * inv;
}

// ---------------- GEMM: Q[i][n] = exp(-1 - dot(Ahat[i], Bhat[n])) = exp(cost-2) ----------------
__global__ __launch_bounds__(256) void gemm_kernel(const float* __restrict__ A, const float* __restrict__ B,
                                                   float* __restrict__ Q) {
    __shared__ float As[16][68];
    __shared__ float Bs[16][68];
    int tid = threadIdx.x;
    int tx = tid & 15, ty = tid >> 4;
    int row0 = blockIdx.y * 64;
    int col0 = blockIdx.x * 64;
    int lrow = tid >> 2;          // 0..63
    int lk = (tid & 3) * 4;       // 0,4,8,12
    const float* ap = A + (size_t)(row0 + lrow) * DIMS + lk;
    const float* bp = B + (size_t)(col0 + lrow) * DIMS + lk;
    float acc[4][4] = {};
    for (int k0 = 0; k0 < DIMS; k0 += 16) {
        float4 av = *(const float4*)ap; ap += 16;
        float4 bv = *(const float4*)bp; bp += 16;
        __syncthreads();
        As[lk + 0][lrow] = av.x; As[lk + 1][lrow] = av.y; As[lk + 2][lrow] = av.z; As[lk + 3][lrow] = av.w;
        Bs[lk + 0][lrow] = bv.x; Bs[lk + 1][lrow] = bv.y; Bs[lk + 2][lrow] = bv.z; Bs[lk + 3][lrow] = bv.w;
        __syncthreads();
        #pragma unroll
        for (int k = 0; k < 16; ++k) {
            float4 a4 = *(const float4*)&As[k][ty * 4];
            float4 b4 = *(const float4*)&Bs[k][tx * 4];
            float aa[4] = {a4.x, a4.y, a4.z, a4.w};
            float bb[4] = {b4.x, b4.y, b4.z, b4.w};
            #pragma unroll
            for (int u = 0; u < 4; ++u)
                #pragma unroll
                for (int v = 0; v < 4; ++v)
                    acc[u][v] += aa[u] * bb[v];
        }
    }
    #pragma unroll
    for (int u = 0; u < 4; ++u) {
        float4 o;
        o.x = __expf(-1.0f - acc[u][0]);
        o.y = __expf(-1.0f - acc[u][1]);
        o.z = __expf(-1.0f - acc[u][2]);
        o.w = __expf(-1.0f - acc[u][3]);
        *(float4*)&Q[(size_t)(row0 + ty * 4 + u) * N_COLS + col0 + tx * 4] = o;
    }
}

// ---------------- per-row softmax denom -> rs2 = log2e/(gamma*denom) ----------------
__global__ __launch_bounds__(256) void rowstat_kernel(const float* __restrict__ Q,
                                                      float* __restrict__ rowscale) {
    int i = blockIdx.x;
    const float* q = Q + (size_t)i * N_COLS;
    int tid = threadIdx.x;
    float4 x = *(const float4*)(q + tid * 4);
    float4 y = *(const float4*)(q + 1024 + tid * 4);
    float s = x.x + x.y + x.z + x.w + y.x + y.y + y.z + y.w;
    #pragma unroll
    for (int off = 32; off > 0; off >>= 1) s += __shfl_down(s, off);
    __shared__ float red[4];
    if ((tid & 63) == 0) red[tid >> 6] = s;
    __syncthreads();
    if (tid == 0) {
        float denom = 2049.0f + red[0] + red[1] + red[2] + red[3];
        rowscale[i] = (LOG2E / GAMMA) / denom;
    }
}

// ---------------- (m,s) pair arithmetic: value = m + log2(s) ----------------
struct Pair { float m, s; };
constexpr float ID_M = -1e30f;

// combine two pairs (log-sum-exp in base 2); one transcendental, no log.
// identity {ID_M, 0} is exact: e = exp2(-inf) = 0.
__device__ __forceinline__ Pair pcomb(Pair a, Pair b) {
    float e = fexp2(-fabsf(a.m - b.m));
    bool c = a.m >= b.m;
    Pair r;
    r.m = c ? a.m : b.m;
    r.s = c ? fmaf(b.s, e, a.s) : fmaf(a.s, e, b.s);
    return r;
}
// exact renormalization: pull s's exponent into m (s -> [1,2)), integer ops only
__device__ __forceinline__ void renorm(float& m, float& s) {
    int bits = __float_as_int(s);
    int ex = ((bits >> 23) & 255) - 127;
    m += (float)ex;
    s = __int_as_float(bits - (ex << 23));
}

// DPP mov with explicit old-value (bound_ctrl=false: invalid/masked lanes keep old)
template<int CTRL, int ROWM>
__device__ __forceinline__ float fdpp(float oldv, float src) {
    return __int_as_float(__builtin_amdgcn_update_dpp(
        __float_as_int(oldv), __float_as_int(src), CTRL, ROWM, 0xF, false));
}
// wave64 inclusive pair-scan, all-DPP (row_shr 1/2/4/8 + row_bcast15 + row_bcast31)
__device__ __forceinline__ Pair wave_incl_scan(Pair v) {
    { float pm = fdpp<0x111,0xF>(ID_M, v.m), ps = fdpp<0x111,0xF>(0.f, v.s); v = pcomb(v, Pair{pm, ps}); }
    { float pm = fdpp<0x112,0xF>(ID_M, v.m), ps = fdpp<0x112,0xF>(0.f, v.s); v = pcomb(v, Pair{pm, ps}); }
    { float pm = fdpp<0x114,0xF>(ID_M, v.m), ps = fdpp<0x114,0xF>(0.f, v.s); v = pcomb(v, Pair{pm, ps}); }
    { float pm = fdpp<0x118,0xF>(ID_M, v.m), ps = fdpp<0x118,0xF>(0.f, v.s); v = pcomb(v, Pair{pm, ps}); }
    { float pm = fdpp<0x142,0xA>(ID_M, v.m), ps = fdpp<0x142,0xA>(0.f, v.s); v = pcomb(v, Pair{pm, ps}); }
    { float pm = fdpp<0x143,0xC>(ID_M, v.m), ps = fdpp<0x143,0xC>(0.f, v.s); v = pcomb(v, Pair{pm, ps}); }
    return v;
}
// exclusive prefix from the inclusive scan result, all-DPP + selects:
// lanes l%16!=0: row_shr:1; lanes 16,48: row_bcast15; lane 32: row_bcast31; lane 0: identity
__device__ __forceinline__ Pair wave_excl_from_incl(Pair v, int lane) {
    float am = fdpp<0x111,0xF>(ID_M, v.m), as_ = fdpp<0x111,0xF>(0.f, v.s);
    float bm = fdpp<0x142,0xA>(ID_M, v.m), bs  = fdpp<0x142,0xA>(0.f, v.s);
    float cm = fdpp<0x143,0x4>(ID_M, v.m), cs  = fdpp<0x143,0x4>(0.f, v.s);
    bool s15 = (lane == 16) || (lane == 48);
    bool s31 = (lane == 32);
    Pair r;
    r.m = s15 ? bm : (s31 ? cm : am);
    r.s = s15 ? bs : (s31 ? cs : as_);
    return r;
}

// ---------------- pipelined multi-block DP: 32 blocks x 1 wave, 1 column/lane ----
// Block b owns P-columns [64b, 64b+64). Per row i:
//   g[lane] = {mP + LG2_i[col], sP}    (LG2 from Q, computed one row ahead, off-chain)
//   DPP wave-inclusive pair-scan (no LDS, no barrier, no bpermute)
//   carry_in from block b-1 (packed u64; lane-0 atomic load poll + readfirstlane bcast)
//   P_new = (cin (+) excl) (+) {mP+lwe, sP};  lane 63 publishes cin (+) incl as carry_out
// Block 31 folds h (column 4096) in lane 63's registers.
// Manual 4x unroll keeps the prefetch ring in registers (dynamic indexing spilled
// to scratch in round 8 -> VGPR_Count 20 and ~1000 cy/row of scratch stalls).
__global__ __launch_bounds__(64) void dp_kernel(const float* __restrict__ Q,
                                                const float* __restrict__ Rs,
                                                unsigned long long* __restrict__ carry,
                                                float* __restrict__ out) {
    const int b = blockIdx.x;
    const int lane = threadIdx.x;
    const float* qcol = Q + b * DP_COLS + lane;

    float mP = 0.f, sP = 1.f;      // virtual row -1: P = log2(1)
    float mH = 0.f, sH = 1.f;      // block 31, lane 63 only

    float qr[4], rr[4];
    #pragma unroll
    for (int k = 0; k < 4; ++k) {
        qr[k] = qcol[(size_t)k * N_COLS];
        rr[k] = Rs[k];
    }
    float rs0 = rr[0];
    float lg_cur = flog2(fexp2(-rs0) + fexp2(-rs0 * qr[0]));
    float lwe_cur = -rs0;

    for (int i = 0; i < M_ROWS; i += 4) {
        #pragma unroll
        for (int u = 0; u < 4; ++u) {
            const int row = i + u;
            // early poll attempt (lane 0 only; overlaps the scan)
            unsigned long long pk = 1ull;
            const unsigned long long* src = carry + (size_t)row * DP_BLOCKS + (b - 1);
            if (b > 0 && lane == 0)
                pk = __hip_atomic_load(src, __ATOMIC_RELAXED, __HIP_MEMORY_SCOPE_AGENT);

            // DPP scan of g = {mP + lg, sP}
            Pair v = wave_incl_scan(Pair{mP + lg_cur, sP});
            Pair excl = wave_excl_from_incl(v, lane);

            // next-row weights from the register ring (off the scan chain)
            float rs1 = rr[(u + 1) & 3];
            float q1  = qr[(u + 1) & 3];
            float lg_nxt  = flog2(fexp2(-rs1) + fexp2(-rs1 * q1));
            float lwe_nxt = -rs1;

            // finish poll; broadcast via readfirstlane (lane 0 is first active lane)
            Pair cin{ID_M, 0.f};
            if (b > 0) {
                if (lane == 0) {
                    while (pk == 0ull)
                        pk = __hip_atomic_load(src, __ATOMIC_RELAXED, __HIP_MEMORY_SCOPE_AGENT);
                }
                unsigned lo = (unsigned)(pk & 0xFFFFFFFFull);
                unsigned hi = (unsigned)(pk >> 32);
                cin.m = __int_as_float(__builtin_amdgcn_readfirstlane((int)lo));
                cin.s = __int_as_float(__builtin_amdgcn_readfirstlane((int)hi));
            }

            if (b < DP_BLOCKS - 1) {
                if (lane == 63) {   // lane 63's inclusive v IS the row total
                    Pair tot = pcomb(cin, v);
                    unsigned long long po = ((unsigned long long)__float_as_uint(tot.s) << 32)
                                          | (unsigned long long)__float_as_uint(tot.m);
                    __hip_atomic_store(carry + (size_t)row * DP_BLOCKS + b, po,
                                       __ATOMIC_RELAXED, __HIP_MEMORY_SCOPE_AGENT);
                }
            } else {
                Pair tot = pcomb(cin, v);           // meaningful on lane 63 only
                Pair hh = pcomb(tot, Pair{mH + lwe_cur, sH});
                mH = hh.m; sH = hh.s;
                renorm(mH, sH);
            }

            // P update
            Pair base = pcomb(cin, excl);
            Pair np = pcomb(base, Pair{mP + lwe_cur, sP});
            mP = np.m; sP = np.s;
            renorm(mP, sP);

            // prefetch row+4 into static slot u
            if (row + 4 < M_ROWS) {
                qr[u] = qcol[(size_t)(row + 4) * N_COLS];
                rr[u] = Rs[row + 4];
            }
            lg_cur = lg_nxt; lwe_cur = lwe_nxt;
        }
    }
    if (b == DP_BLOCKS - 1 && lane == 63)
        out[0] = -GAMMA * LN2 * (mH + flog2(sH));
}

extern "C" void kernel_launch(void* const* d_in, const int* in_sizes, int n_in,
                              void* d_out, int out_size, void* d_ws, size_t ws_size,
                              hipStream_t stream) {
    (void)in_sizes; (void)n_in; (void)out_size; (void)ws_size;
    const float* a = (const float*)d_in[0];
    const float* b = (const float*)d_in[1];
    float* out = (float*)d_out;
    char* ws = (char*)d_ws;
    float* Q        = (float*)(ws);                                    // 16 MB
    float* Ahat     = (float*)(ws + (size_t)16 * 1024 * 1024);         // 4 MB
    float* Bhat     = (float*)(ws + (size_t)20 * 1024 * 1024);         // 4 MB
    float* rowscale = (float*)(ws + (size_t)24 * 1024 * 1024);         // 8 KB
    int* permA      = (int*)(ws + (size_t)24 * 1024 * 1024 + 8192);    // 8 KB
    int* permB      = (int*)(ws + (size_t)24 * 1024 * 1024 + 16384);   // 8 KB
    unsigned long long* carry = (unsigned long long*)(ws + (size_t)25 * 1024 * 1024); // 512 KB

    hipMemsetAsync(carry, 0, (size_t)M_ROWS * DP_BLOCKS * sizeof(unsigned long long), stream);
    argsort_kernel<<<dim3(8, 2), 256, 0, stream>>>(a, b, permA, permB);
    norm_kernel<<<dim3(2048, 2), 128, 0, stream>>>(a, b, permA, permB, Ahat, Bhat);
    gemm_kernel<<<dim3(32, 32), 256, 0, stream>>>(Ahat, Bhat, Q);
    rowstat_kernel<<<2048, 256, 0, stream>>>(Q, rowscale);
    dp_kernel<<<DP_BLOCKS, DP_COLS, 0, stream>>>(Q, rowscale, carry, out);
}

// Round 10
// 1158.133 us; speedup vs baseline: 2.5935x; 1.7242x over previous
//
#include <hip/hip_runtime.h>
#include <math.h>

#define M_ROWS 2048
#define N_COLS 2048
#define DIMS 512
#define IN_STRIDE 513
#define DP_BLOCKS 32
#define DP_COLS 64
#define BAND 16

constexpr float GAMMA = 0.001f;
constexpr float LOG2E = 1.44269504088896f;
constexpr float LN2   = 0.69314718055995f;

// hardware base-2 exp/log (v_exp_f32 / v_log_f32). NOTE: __exp2f/__log2f collide
// with glibc math.h internals on this toolchain — use the amdgcn builtins.
__device__ __forceinline__ float fexp2(float x) { return __builtin_amdgcn_exp2f(x); }
__device__ __forceinline__ float flog2(float x) { return __builtin_amdgcn_logf(x); }

// ---------------- argsort by timestamp (last column), stable ----------------
__global__ void argsort_kernel(const float* __restrict__ a, const float* __restrict__ b,
                               int* __restrict__ permA, int* __restrict__ permB) {
    const float* src = blockIdx.y ? b : a;
    int* perm = blockIdx.y ? permB : permA;
    __shared__ float keys[M_ROWS];
    for (int j = threadIdx.x; j < M_ROWS; j += blockDim.x)
        keys[j] = src[(size_t)j * IN_STRIDE + DIMS];
    __syncthreads();
    int i = blockIdx.x * blockDim.x + threadIdx.x;
    float ki = keys[i];
    int rank = 0;
    for (int j = 0; j < M_ROWS; ++j) {
        float kj = keys[j];
        rank += (kj < ki) || (kj == ki && j < i);  // stable rank
    }
    perm[rank] = i;
}

// ---------------- gather sorted rows + L2-normalize (drop time col) ----------------
__global__ __launch_bounds__(128) void norm_kernel(const float* __restrict__ a, const float* __restrict__ b,
                                                   const int* __restrict__ permA, const int* __restrict__ permB,
                                                   float* __restrict__ Ahat, float* __restrict__ Bhat) {
    const float* src = blockIdx.y ? b : a;
    const int* perm = blockIdx.y ? permB : permA;
    float* dst = blockIdx.y ? Bhat : Ahat;
    int r = blockIdx.x;
    int row = perm[r];
    const float* p = src + (size_t)row * IN_STRIDE;
    int tid = threadIdx.x;
    float v0 = p[tid], v1 = p[tid + 128], v2 = p[tid + 256], v3 = p[tid + 384];
    float ss = v0 * v0 + v1 * v1 + v2 * v2 + v3 * v3;
    #pragma unroll
    for (int off = 32; off > 0; off >>= 1) ss += __shfl_down(ss, off);
    __shared__ float red[2];
    if ((tid & 63) == 0) red[tid >> 6] = ss;
    __syncthreads();
    float inv = 1.0f / sqrtf(red[0] + red[1] + 1e-10f);
    float* q = dst + (size_t)r * DIMS;
    q[tid] = v0 * inv; q[tid + 128] = v1 * inv; q[tid + 256] = v2 * inv; q[tid + 384] = v3 * inv;
}

// ---------------- GEMM: Q[i][n] = exp(-1 - dot(Ahat[i], Bhat[n])) = exp(cost-2) ----------------
__global__ __launch_bounds__(256) void gemm_kernel(const float* __restrict__ A, const float* __restrict__ B,
                                                   float* __restrict__ Q) {
    __shared__ float As[16][68];
    __shared__ float Bs[16][68];
    int tid = threadIdx.x;
    int tx = tid & 15, ty = tid >> 4;
    int row0 = blockIdx.y * 64;
    int col0 = blockIdx.x * 64;
    int lrow = tid >> 2;          // 0..63
    int lk = (tid & 3) * 4;       // 0,4,8,12
    const float* ap = A + (size_t)(row0 + lrow) * DIMS + lk;
    const float* bp = B + (size_t)(col0 + lrow) * DIMS + lk;
    float acc[4][4] = {};
    for (int k0 = 0; k0 < DIMS; k0 += 16) {
        float4 av = *(const float4*)ap; ap += 16;
        float4 bv = *(const float4*)bp; bp += 16;
        __syncthreads();
        As[lk + 0][lrow] = av.x; As[lk + 1][lrow] = av.y; As[lk + 2][lrow] = av.z; As[lk + 3][lrow] = av.w;
        Bs[lk + 0][lrow] = bv.x; Bs[lk + 1][lrow] = bv.y; Bs[lk + 2][lrow] = bv.z; Bs[lk + 3][lrow] = bv.w;
        __syncthreads();
        #pragma unroll
        for (int k = 0; k < 16; ++k) {
            float4 a4 = *(const float4*)&As[k][ty * 4];
            float4 b4 = *(const float4*)&Bs[k][tx * 4];
            float aa[4] = {a4.x, a4.y, a4.z, a4.w};
            float bb[4] = {b4.x, b4.y, b4.z, b4.w};
            #pragma unroll
            for (int u = 0; u < 4; ++u)
                #pragma unroll
                for (int v = 0; v < 4; ++v)
                    acc[u][v] += aa[u] * bb[v];
        }
    }
    #pragma unroll
    for (int u = 0; u < 4; ++u) {
        float4 o;
        o.x = __expf(-1.0f - acc[u][0]);
        o.y = __expf(-1.0f - acc[u][1]);
        o.z = __expf(-1.0f - acc[u][2]);
        o.w = __expf(-1.0f - acc[u][3]);
        *(float4*)&Q[(size_t)(row0 + ty * 4 + u) * N_COLS + col0 + tx * 4] = o;
    }
}

// ---------------- per-row softmax denom -> rs2 = log2e/(gamma*denom) ----------------
__global__ __launch_bounds__(256) void rowstat_kernel(const float* __restrict__ Q,
                                                      float* __restrict__ rowscale) {
    int i = blockIdx.x;
    const float* q = Q + (size_t)i * N_COLS;
    int tid = threadIdx.x;
    float4 x = *(const float4*)(q + tid * 4);
    float4 y = *(const float4*)(q + 1024 + tid * 4);
    float s = x.x + x.y + x.z + x.w + y.x + y.y + y.z + y.w;
    #pragma unroll
    for (int off = 32; off > 0; off >>= 1) s += __shfl_down(s, off);
    __shared__ float red[4];
    if ((tid & 63) == 0) red[tid >> 6] = s;
    __syncthreads();
    if (tid == 0) {
        float denom = 2049.0f + red[0] + red[1] + red[2] + red[3];
        rowscale[i] = (LOG2E / GAMMA) / denom;
    }
}

// ---------------- (m,s) pair arithmetic: value = m + log2(s) ----------------
struct Pair { float m, s; };
constexpr float ID_M = -1e30f;

// combine two pairs (log-sum-exp in base 2); one transcendental, no log.
// identity {ID_M, 0} is exact: e = exp2(-inf) = 0.
__device__ __forceinline__ Pair pcomb(Pair a, Pair b) {
    float e = fexp2(-fabsf(a.m - b.m));
    bool c = a.m >= b.m;
    Pair r;
    r.m = c ? a.m : b.m;
    r.s = c ? fmaf(b.s, e, a.s) : fmaf(a.s, e, b.s);
    return r;
}
// exact renormalization: pull s's exponent into m (s -> [1,2)), integer ops only
__device__ __forceinline__ void renorm(float& m, float& s) {
    int bits = __float_as_int(s);
    int ex = ((bits >> 23) & 255) - 127;
    m += (float)ex;
    s = __int_as_float(bits - (ex << 23));
}

// DPP mov with explicit old-value (bound_ctrl=false: invalid/masked lanes keep old)
template<int CTRL, int ROWM>
__device__ __forceinline__ float fdpp(float oldv, float src) {
    return __int_as_float(__builtin_amdgcn_update_dpp(
        __float_as_int(oldv), __float_as_int(src), CTRL, ROWM, 0xF, false));
}
// wave64 inclusive pair-scan, all-DPP (row_shr 1/2/4/8 + row_bcast15 + row_bcast31)
__device__ __forceinline__ Pair wave_incl_scan(Pair v) {
    { float pm = fdpp<0x111,0xF>(ID_M, v.m), ps = fdpp<0x111,0xF>(0.f, v.s); v = pcomb(v, Pair{pm, ps}); }
    { float pm = fdpp<0x112,0xF>(ID_M, v.m), ps = fdpp<0x112,0xF>(0.f, v.s); v = pcomb(v, Pair{pm, ps}); }
    { float pm = fdpp<0x114,0xF>(ID_M, v.m), ps = fdpp<0x114,0xF>(0.f, v.s); v = pcomb(v, Pair{pm, ps}); }
    { float pm = fdpp<0x118,0xF>(ID_M, v.m), ps = fdpp<0x118,0xF>(0.f, v.s); v = pcomb(v, Pair{pm, ps}); }
    { float pm = fdpp<0x142,0xA>(ID_M, v.m), ps = fdpp<0x142,0xA>(0.f, v.s); v = pcomb(v, Pair{pm, ps}); }
    { float pm = fdpp<0x143,0xC>(ID_M, v.m), ps = fdpp<0x143,0xC>(0.f, v.s); v = pcomb(v, Pair{pm, ps}); }
    return v;
}
// exclusive prefix from the inclusive scan result, all-DPP + selects:
// lanes l%16!=0: row_shr:1; lanes 16,48: row_bcast15; lane 32: row_bcast31; lane 0: identity
__device__ __forceinline__ Pair wave_excl_from_incl(Pair v, int lane) {
    float am = fdpp<0x111,0xF>(ID_M, v.m), as_ = fdpp<0x111,0xF>(0.f, v.s);
    float bm = fdpp<0x142,0xA>(ID_M, v.m), bs  = fdpp<0x142,0xA>(0.f, v.s);
    float cm = fdpp<0x143,0x4>(ID_M, v.m), cs  = fdpp<0x143,0x4>(0.f, v.s);
    bool s15 = (lane == 16) || (lane == 48);
    bool s31 = (lane == 32);
    Pair r;
    r.m = s15 ? bm : (s31 ? cm : am);
    r.s = s15 ? bs : (s31 ? cs : as_);
    return r;
}

// ---------------- pipelined multi-block DP with BANDED carry exchange ----------------
// 32 single-wave blocks; logical stripe s owns P-columns [64s, 64s+64), 1 col/lane.
// Carries are exchanged in bands of BAND=16 rows: lanes 0..15 each spin on their own
// row's carry (one coalesced vector load per spin iteration), then 16 rows run with
// carries in registers (readlane with static index) — the cross-block load latency
// is amortized 16x instead of sitting on every row's chain (round 9: ~1900 cy/row).
// Carry layout [stripe][row] so band polls are 128B-contiguous. XCD-aware swizzle:
// s = (blk&7)*4 + blk>>3 keeps 3 of 4 hops on one XCD's L2.
__global__ __launch_bounds__(64) void dp_kernel(const float* __restrict__ Q,
                                                const float* __restrict__ Rs,
                                                unsigned long long* __restrict__ carry,
                                                float* __restrict__ out) {
    const int s = ((blockIdx.x & 7) << 2) | (blockIdx.x >> 3);
    const int lane = threadIdx.x;
    const float* qcol = Q + s * DP_COLS + lane;
    unsigned long long* pub = carry + (size_t)s * M_ROWS;
    const unsigned long long* sub = carry + (size_t)(s - 1) * M_ROWS;

    float mP = 0.f, sP = 1.f;      // virtual row -1: P = log2(1)
    float mH = 0.f, sH = 1.f;      // stripe 31, lane 63 only

    // register ring: slot u holds row (base+u)'s Q/Rs; refilled with +BAND after use
    float qr[BAND], rr[BAND];
    #pragma unroll
    for (int k = 0; k < BAND; ++k) {
        qr[k] = qcol[(size_t)k * N_COLS];
        rr[k] = Rs[k];
    }
    float rs0 = rr[0];
    float lg_cur = flog2(fexp2(-rs0) + fexp2(-rs0 * qr[0]));
    float lwe_cur = -rs0;

    for (int base = 0; base < M_ROWS; base += BAND) {
        // band poll: lane u<16 spins on its own row's carry (per-lane divergent spin)
        unsigned long long pk = 1ull;
        if (s > 0 && lane < BAND) {
            const unsigned long long* p = sub + base + lane;
            do {
                pk = __hip_atomic_load(p, __ATOMIC_RELAXED, __HIP_MEMORY_SCOPE_AGENT);
            } while (pk == 0ull);
        }
        int pkLo = (int)(unsigned)(pk & 0xFFFFFFFFull);
        int pkHi = (int)(unsigned)(pk >> 32);

        #pragma unroll
        for (int u = 0; u < BAND; ++u) {
            const int row = base + u;

            // DPP scan of g = {mP + lg, sP}
            Pair v = wave_incl_scan(Pair{mP + lg_cur, sP});
            Pair excl = wave_excl_from_incl(v, lane);

            // next-row weights from the register ring (off the scan chain)
            float rs1 = rr[(u + 1) & (BAND - 1)];
            float q1  = qr[(u + 1) & (BAND - 1)];
            float lg_nxt  = flog2(fexp2(-rs1) + fexp2(-rs1 * q1));
            float lwe_nxt = -rs1;

            // carry-in for this row from lane u's polled value (static lane index)
            Pair cin{ID_M, 0.f};
            if (s > 0) {
                cin.m = __int_as_float(__builtin_amdgcn_readlane(pkLo, u));
                cin.s = __int_as_float(__builtin_amdgcn_readlane(pkHi, u));
            }

            if (s < DP_BLOCKS - 1) {
                if (lane == 63) {   // lane 63's inclusive v IS the row total
                    Pair tot = pcomb(cin, v);
                    unsigned long long po = ((unsigned long long)__float_as_uint(tot.s) << 32)
                                          | (unsigned long long)__float_as_uint(tot.m);
                    __hip_atomic_store(pub + row, po,
                                       __ATOMIC_RELAXED, __HIP_MEMORY_SCOPE_AGENT);
                }
            } else {
                Pair tot = pcomb(cin, v);           // meaningful on lane 63 only
                Pair hh = pcomb(tot, Pair{mH + lwe_cur, sH});
                mH = hh.m; sH = hh.s;
                renorm(mH, sH);
            }

            // P update
            Pair bse = pcomb(cin, excl);
            Pair np = pcomb(bse, Pair{mP + lwe_cur, sP});
            mP = np.m; sP = np.s;
            renorm(mP, sP);

            // refill ring slot u with row+BAND (next band), off the chain
            if (row + BAND < M_ROWS) {
                qr[u] = qcol[(size_t)(row + BAND) * N_COLS];
                rr[u] = Rs[row + BAND];
            }
            lg_cur = lg_nxt; lwe_cur = lwe_nxt;
        }
    }
    if (s == DP_BLOCKS - 1 && lane == 63)
        out[0] = -GAMMA * LN2 * (mH + flog2(sH));
}

extern "C" void kernel_launch(void* const* d_in, const int* in_sizes, int n_in,
                              void* d_out, int out_size, void* d_ws, size_t ws_size,
                              hipStream_t stream) {
    (void)in_sizes; (void)n_in; (void)out_size; (void)ws_size;
    const float* a = (const float*)d_in[0];
    const float* b = (const float*)d_in[1];
    float* out = (float*)d_out;
    char* ws = (char*)d_ws;
    float* Q        = (float*)(ws);                                    // 16 MB
    float* Ahat     = (float*)(ws + (size_t)16 * 1024 * 1024);         // 4 MB
    float* Bhat     = (float*)(ws + (size_t)20 * 1024 * 1024);         // 4 MB
    float* rowscale = (float*)(ws + (size_t)24 * 1024 * 1024);         // 8 KB
    int* permA      = (int*)(ws + (size_t)24 * 1024 * 1024 + 8192);    // 8 KB
    int* permB      = (int*)(ws + (size_t)24 * 1024 * 1024 + 16384);   // 8 KB
    unsigned long long* carry = (unsigned long long*)(ws + (size_t)25 * 1024 * 1024); // 512 KB

    hipMemsetAsync(carry, 0, (size_t)DP_BLOCKS * M_ROWS * sizeof(unsigned long long), stream);
    argsort_kernel<<<dim3(8, 2), 256, 0, stream>>>(a, b, permA, permB);
    norm_kernel<<<dim3(2048, 2), 128, 0, stream>>>(a, b, permA, permB, Ahat, Bhat);
    gemm_kernel<<<dim3(32, 32), 256, 0, stream>>>(Ahat, Bhat, Q);
    rowstat_kernel<<<2048, 256, 0, stream>>>(Q, rowscale);
    dp_kernel<<<DP_BLOCKS, DP_COLS, 0, stream>>>(Q, rowscale, carry, out);
}

// Round 12
// 1141.865 us; speedup vs baseline: 2.6304x; 1.0142x over previous
//
#include <hip/hip_runtime.h>
#include <math.h>

#define M_ROWS 2048
#define N_COLS 2048
#define DIMS 512
#define IN_STRIDE 513
#define DP_BLOCKS 32
#define DP_COLS 64
#define BAND 16

constexpr float GAMMA = 0.001f;
constexpr float LOG2E = 1.44269504088896f;
constexpr float LN2   = 0.69314718055995f;

// hardware base-2 exp/log (v_exp_f32 / v_log_f32). NOTE: __exp2f/__log2f collide
// with glibc math.h internals on this toolchain — use the amdgcn builtins.
__device__ __forceinline__ float fexp2(float x) { return __builtin_amdgcn_exp2f(x); }
__device__ __forceinline__ float flog2(float x) { return __builtin_amdgcn_logf(x); }

// ---------------- argsort by timestamp (last column), stable ----------------
__global__ void argsort_kernel(const float* __restrict__ a, const float* __restrict__ b,
                               int* __restrict__ permA, int* __restrict__ permB) {
    const float* src = blockIdx.y ? b : a;
    int* perm = blockIdx.y ? permB : permA;
    __shared__ float keys[M_ROWS];
    for (int j = threadIdx.x; j < M_ROWS; j += blockDim.x)
        keys[j] = src[(size_t)j * IN_STRIDE + DIMS];
    __syncthreads();
    int i = blockIdx.x * blockDim.x + threadIdx.x;
    float ki = keys[i];
    int rank = 0;
    for (int j = 0; j < M_ROWS; ++j) {
        float kj = keys[j];
        rank += (kj < ki) || (kj == ki && j < i);  // stable rank
    }
    perm[rank] = i;
}

// ---------------- gather sorted rows + L2-normalize (drop time col) ----------------
__global__ __launch_bounds__(128) void norm_kernel(const float* __restrict__ a, const float* __restrict__ b,
                                                   const int* __restrict__ permA, const int* __restrict__ permB,
                                                   float* __restrict__ Ahat, float* __restrict__ Bhat) {
    const float* src = blockIdx.y ? b : a;
    const int* perm = blockIdx.y ? permB : permA;
    float* dst = blockIdx.y ? Bhat : Ahat;
    int r = blockIdx.x;
    int row = perm[r];
    const float* p = src + (size_t)row * IN_STRIDE;
    int tid = threadIdx.x;
    float v0 = p[tid], v1 = p[tid + 128], v2 = p[tid + 256], v3 = p[tid + 384];
    float ss = v0 * v0 + v1 * v1 + v2 * v2 + v3 * v3;
    #pragma unroll
    for (int off = 32; off > 0; off >>= 1) ss += __shfl_down(ss, off);
    __shared__ float red[2];
    if ((tid & 63) == 0) red[tid >> 6] = ss;
    __syncthreads();
    float inv = 1.0f / sqrtf(red[0] + red[1] + 1e-10f);
    float* q = dst + (size_t)r * DIMS;
    q[tid] = v0 * inv; q[tid + 128] = v1 * inv; q[tid + 256] = v2 * inv; q[tid + 384] = v3 * inv;
}

// ---------------- GEMM: Q[i][n] = exp(-1 - dot(Ahat[i], Bhat[n])) = exp(cost-2) ----------------
__global__ __launch_bounds__(256) void gemm_kernel(const float* __restrict__ A, const float* __restrict__ B,
                                                   float* __restrict__ Q) {
    __shared__ float As[16][68];
    __shared__ float Bs[16][68];
    int tid = threadIdx.x;
    int tx = tid & 15, ty = tid >> 4;
    int row0 = blockIdx.y * 64;
    int col0 = blockIdx.x * 64;
    int lrow = tid >> 2;          // 0..63
    int lk = (tid & 3) * 4;       // 0,4,8,12
    const float* ap = A + (size_t)(row0 + lrow) * DIMS + lk;
    const float* bp = B + (size_t)(col0 + lrow) * DIMS + lk;
    float acc[4][4] = {};
    for (int k0 = 0; k0 < DIMS; k0 += 16) {
        float4 av = *(const float4*)ap; ap += 16;
        float4 bv = *(const float4*)bp; bp += 16;
        __syncthreads();
        As[lk + 0][lrow] = av.x; As[lk + 1][lrow] = av.y; As[lk + 2][lrow] = av.z; As[lk + 3][lrow] = av.w;
        Bs[lk + 0][lrow] = bv.x; Bs[lk + 1][lrow] = bv.y; Bs[lk + 2][lrow] = bv.z; Bs[lk + 3][lrow] = bv.w;
        __syncthreads();
        #pragma unroll
        for (int k = 0; k < 16; ++k) {
            float4 a4 = *(const float4*)&As[k][ty * 4];
            float4 b4 = *(const float4*)&Bs[k][tx * 4];
            float aa[4] = {a4.x, a4.y, a4.z, a4.w};
            float bb[4] = {b4.x, b4.y, b4.z, b4.w};
            #pragma unroll
            for (int u = 0; u < 4; ++u)
                #pragma unroll
                for (int v = 0; v < 4; ++v)
                    acc[u][v] += aa[u] * bb[v];
        }
    }
    #pragma unroll
    for (int u = 0; u < 4; ++u) {
        float4 o;
        o.x = __expf(-1.0f - acc[u][0]);
        o.y = __expf(-1.0f - acc[u][1]);
        o.z = __expf(-1.0f - acc[u][2]);
        o.w = __expf(-1.0f - acc[u][3]);
        *(float4*)&Q[(size_t)(row0 + ty * 4 + u) * N_COLS + col0 + tx * 4] = o;
    }
}

// ---------------- per-row softmax denom -> rs2 = log2e/(gamma*denom) ----------------
__global__ __launch_bounds__(256) void rowstat_kernel(const float* __restrict__ Q,
                                                      float* __restrict__ rowscale) {
    int i = blockIdx.x;
    const float* q = Q + (size_t)i * N_COLS;
    int tid = threadIdx.x;
    float4 x = *(const float4*)(q + tid * 4);
    float4 y = *(const float4*)(q + 1024 + tid * 4);
    float s = x.x + x.y + x.z + x.w + y.x + y.y + y.z + y.w;
    #pragma unroll
    for (int off = 32; off > 0; off >>= 1) s += __shfl_down(s, off);
    __shared__ float red[4];
    if ((tid & 63) == 0) red[tid >> 6] = s;
    __syncthreads();
    if (tid == 0) {
        float denom = 2049.0f + red[0] + red[1] + red[2] + red[3];
        rowscale[i] = (LOG2E / GAMMA) / denom;
    }
}

// ---------------- (m,s) pair arithmetic: value = m + log2(s) ----------------
struct Pair { float m, s; };
constexpr float ID_M = -1e30f;

// combine two pairs (log-sum-exp in base 2); one transcendental, no log.
__device__ __forceinline__ Pair pcomb(Pair a, Pair b) {
    float e = fexp2(-fabsf(a.m - b.m));
    bool c = a.m >= b.m;
    Pair r;
    r.m = c ? a.m : b.m;
    r.s = c ? fmaf(b.s, e, a.s) : fmaf(a.s, e, b.s);
    return r;
}
// exact renormalization: pull s's exponent into m (s -> [1,2)), integer ops only
__device__ __forceinline__ void renorm(float& m, float& s) {
    int bits = __float_as_int(s);
    int ex = ((bits >> 23) & 255) - 127;
    m += (float)ex;
    s = __int_as_float(bits - (ex << 23));
}

// DPP mov with explicit old-value (bound_ctrl=false: invalid/masked lanes keep old)
template<int CTRL, int ROWM>
__device__ __forceinline__ float fdpp(float oldv, float src) {
    return __int_as_float(__builtin_amdgcn_update_dpp(
        __float_as_int(oldv), __float_as_int(src), CTRL, ROWM, 0xF, false));
}

// wave64 inclusive MAX-scan (no transcendentals on the chain)
__device__ __forceinline__ float wave_max_scan(float m) {
    m = fmaxf(m, fdpp<0x111,0xF>(ID_M, m));
    m = fmaxf(m, fdpp<0x112,0xF>(ID_M, m));
    m = fmaxf(m, fdpp<0x114,0xF>(ID_M, m));
    m = fmaxf(m, fdpp<0x118,0xF>(ID_M, m));
    m = fmaxf(m, fdpp<0x142,0xA>(ID_M, m));
    m = fmaxf(m, fdpp<0x143,0xC>(ID_M, m));
    return m;
}
// wave64 inclusive AFFINE scan: S[n] = S[n-1]*a[n] + z[n].
// State (A,S) over a lane segment; composition (Ap,Sp)∘(Ac,Sc) = (Ap*Ac, Sp*Ac+Sc).
// Identity for missing prev: (1, 0). mul+fma only — no transcendentals.
__device__ __forceinline__ void affine_scan(float& A, float& S) {
    { float Ap = fdpp<0x111,0xF>(1.0f, A), Sp = fdpp<0x111,0xF>(0.0f, S); S = fmaf(Sp, A, S); A = A * Ap; }
    { float Ap = fdpp<0x112,0xF>(1.0f, A), Sp = fdpp<0x112,0xF>(0.0f, S); S = fmaf(Sp, A, S); A = A * Ap; }
    { float Ap = fdpp<0x114,0xF>(1.0f, A), Sp = fdpp<0x114,0xF>(0.0f, S); S = fmaf(Sp, A, S); A = A * Ap; }
    { float Ap = fdpp<0x118,0xF>(1.0f, A), Sp = fdpp<0x118,0xF>(0.0f, S); S = fmaf(Sp, A, S); A = A * Ap; }
    { float Ap = fdpp<0x142,0xA>(1.0f, A), Sp = fdpp<0x142,0xA>(0.0f, S); S = fmaf(Sp, A, S); A = A * Ap; }
    { float Ap = fdpp<0x143,0xC>(1.0f, A), Sp = fdpp<0x143,0xC>(0.0f, S); S = fmaf(Sp, A, S); A = A * Ap; }
}
// lane (n-1) value of x, crossing 16-lane DPP row boundaries:
// in-row lanes: row_shr:1; lanes 16,48: row_bcast15; lane 32: row_bcast31; lane 0: idv.
// (round 11's NaN: using row_shr:1 alone left lanes 16/32/48 with oldv.)
__device__ __forceinline__ float lane_prev(float x, int lane, float idv) {
    float am = fdpp<0x111,0xF>(idv, x);
    float bm = fdpp<0x142,0xA>(idv, x);
    float cm = fdpp<0x143,0x4>(idv, x);
    bool s15 = (lane == 16) || (lane == 48);
    bool s31 = (lane == 32);
    return s15 ? bm : (s31 ? cm : am);
}

// ---------------- pipelined multi-block DP, banded carries, affine-scan rows ----------
// 32 single-wave blocks; stripe s owns P-columns [64s, 64s+64), 1 col/lane.
// Per row: g = mP + LG2; M = max-scan(g); a = 2^(M[n-1]-M[n]); z = sP*2^(g-M);
// affine-scan -> inclusive prefix pair {M, S}; excl = {M[n-1], S[n-1]}; P_new =
// 3-way LSE (cin, excl, {mP+lwe, sP}) with ONE parallel exp2 level (round 10's
// chain had 9 serial v_exp_f32; this has 1-2).
__global__ __launch_bounds__(64) void dp_kernel(const float* __restrict__ Q,
                                                const float* __restrict__ Rs,
                                                unsigned long long* __restrict__ carry,
                                                float* __restrict__ out) {
    const int s = ((blockIdx.x & 7) << 2) | (blockIdx.x >> 3);  // XCD-aware stripe id
    const int lane = threadIdx.x;
    const float* qcol = Q + s * DP_COLS + lane;
    unsigned long long* pub = carry + (size_t)s * M_ROWS;
    const unsigned long long* sub = carry + (size_t)(s - 1) * M_ROWS;

    float mP = 0.f, sP = 1.f;      // virtual row -1: P = log2(1)
    float mH = 0.f, sH = 1.f;      // stripe 31, lane 63 only

    float qr[BAND], rr[BAND];
    #pragma unroll
    for (int k = 0; k < BAND; ++k) {
        qr[k] = qcol[(size_t)k * N_COLS];
        rr[k] = Rs[k];
    }
    float rs0 = rr[0];
    float lg_cur = flog2(fexp2(-rs0) + fexp2(-rs0 * qr[0]));
    float lwe_cur = -rs0;

    for (int base = 0; base < M_ROWS; base += BAND) {
        // band poll: lane u<16 spins on its own row's carry
        unsigned long long pk = 1ull;
        if (s > 0 && lane < BAND) {
            const unsigned long long* p = sub + base + lane;
            do {
                pk = __hip_atomic_load(p, __ATOMIC_RELAXED, __HIP_MEMORY_SCOPE_AGENT);
            } while (pk == 0ull);
        }
        int pkLo = (int)(unsigned)(pk & 0xFFFFFFFFull);
        int pkHi = (int)(unsigned)(pk >> 32);

        #pragma unroll
        for (int u = 0; u < BAND; ++u) {
            const int row = base + u;

            // ---- row chain: max-scan + affine scan (no serial trans) ----
            float g = mP + lg_cur;
            float M = wave_max_scan(g);
            float Mp = lane_prev(M, lane, ID_M);          // M[n-1], boundary-correct
            float a = (lane == 0) ? 1.0f : fexp2(Mp - M); // a in [0,1]
            float z = sP * fexp2(g - M);                  // both exp2 parallel
            float A = a, S = z;
            affine_scan(A, S);
            // exclusive prefix pair {M[n-1], S[n-1]}
            float Sp_ = lane_prev(S, lane, 0.0f);
            Pair ex{(lane == 0) ? ID_M : Mp, (lane == 0) ? 0.f : Sp_};

            // next-row weights from the register ring (off the chain)
            float rs1 = rr[(u + 1) & (BAND - 1)];
            float q1  = qr[(u + 1) & (BAND - 1)];
            float lg_nxt  = flog2(fexp2(-rs1) + fexp2(-rs1 * q1));
            float lwe_nxt = -rs1;

            // carry-in for this row (static lane index readlane)
            Pair cin{ID_M, 0.f};
            if (s > 0) {
                cin.m = __int_as_float(__builtin_amdgcn_readlane(pkLo, u));
                cin.s = __int_as_float(__builtin_amdgcn_readlane(pkHi, u));
            }

            Pair v{M, S};                                  // inclusive prefix pair
            if (s < DP_BLOCKS - 1) {
                if (lane == 63) {   // lane 63's inclusive v IS the row total
                    Pair tot = pcomb(cin, v);
                    unsigned long long po = ((unsigned long long)__float_as_uint(tot.s) << 32)
                                          | (unsigned long long)__float_as_uint(tot.m);
                    __hip_atomic_store(pub + row, po,
                                       __ATOMIC_RELAXED, __HIP_MEMORY_SCOPE_AGENT);
                }
            } else {
                Pair tot = pcomb(cin, v);           // meaningful on lane 63 only
                Pair hh = pcomb(tot, Pair{mH + lwe_cur, sH});
                mH = hh.m; sH = hh.s;
                renorm(mH, sH);
            }

            // P update: 3-way LSE with one shared max (single parallel exp2 level)
            float dm = mP + lwe_cur;
            float m3 = fmaxf(fmaxf(cin.m, ex.m), dm);
            float s3 = cin.s * fexp2(cin.m - m3)
                     + ex.s  * fexp2(ex.m  - m3)
                     + sP    * fexp2(dm    - m3);
            mP = m3; sP = s3;
            renorm(mP, sP);

            // refill ring slot u with row+BAND (off the chain)
            if (row + BAND < M_ROWS) {
                qr[u] = qcol[(size_t)(row + BAND) * N_COLS];
                rr[u] = Rs[row + BAND];
            }
            lg_cur = lg_nxt; lwe_cur = lwe_nxt;
        }
    }
    if (s == DP_BLOCKS - 1 && lane == 63)
        out[0] = -GAMMA * LN2 * (mH + flog2(sH));
}

extern "C" void kernel_launch(void* const* d_in, const int* in_sizes, int n_in,
                              void* d_out, int out_size, void* d_ws, size_t ws_size,
                              hipStream_t stream) {
    (void)in_sizes; (void)n_in; (void)out_size; (void)ws_size;
    const float* a = (const float*)d_in[0];
    const float* b = (const float*)d_in[1];
    float* out = (float*)d_out;
    char* ws = (char*)d_ws;
    float* Q        = (float*)(ws);                                    // 16 MB
    float* Ahat     = (float*)(ws + (size_t)16 * 1024 * 1024);         // 4 MB
    float* Bhat     = (float*)(ws + (size_t)20 * 1024 * 1024);         // 4 MB
    float* rowscale = (float*)(ws + (size_t)24 * 1024 * 1024);         // 8 KB
    int* permA      = (int*)(ws + (size_t)24 * 1024 * 1024 + 8192);    // 8 KB
    int* permB      = (int*)(ws + (size_t)24 * 1024 * 1024 + 16384);   // 8 KB
    unsigned long long* carry = (unsigned long long*)(ws + (size_t)25 * 1024 * 1024); // 512 KB

    hipMemsetAsync(carry, 0, (size_t)DP_BLOCKS * M_ROWS * sizeof(unsigned long long), stream);
    argsort_kernel<<<dim3(8, 2), 256, 0, stream>>>(a, b, permA, permB);
    norm_kernel<<<dim3(2048, 2), 128, 0, stream>>>(a, b, permA, permB, Ahat, Bhat);
    gemm_kernel<<<dim3(32, 32), 256, 0, stream>>>(Ahat, Bhat, Q);
    rowstat_kernel<<<2048, 256, 0, stream>>>(Q, rowscale);
    dp_kernel<<<DP_BLOCKS, DP_COLS, 0, stream>>>(Q, rowscale, carry, out);
}

// Round 13
// 984.068 us; speedup vs baseline: 3.0522x; 1.1604x over previous
//
#include <hip/hip_runtime.h>
#include <math.h>

#define M_ROWS 2048
#define N_COLS 2048
#define DIMS 512
#define IN_STRIDE 513
#define DP_BLOCKS 32
#define DP_COLS 64
#define BAND 16

constexpr float GAMMA = 0.001f;
constexpr float LOG2E = 1.44269504088896f;
constexpr float LN2   = 0.69314718055995f;

// hardware base-2 exp/log (v_exp_f32 / v_log_f32). NOTE: __exp2f/__log2f collide
// with glibc math.h internals on this toolchain — use the amdgcn builtins.
__device__ __forceinline__ float fexp2(float x) { return __builtin_amdgcn_exp2f(x); }
__device__ __forceinline__ float flog2(float x) { return __builtin_amdgcn_logf(x); }

// ---------------- argsort by timestamp (last column), stable ----------------
__global__ void argsort_kernel(const float* __restrict__ a, const float* __restrict__ b,
                               int* __restrict__ permA, int* __restrict__ permB) {
    const float* src = blockIdx.y ? b : a;
    int* perm = blockIdx.y ? permB : permA;
    __shared__ float keys[M_ROWS];
    for (int j = threadIdx.x; j < M_ROWS; j += blockDim.x)
        keys[j] = src[(size_t)j * IN_STRIDE + DIMS];
    __syncthreads();
    int i = blockIdx.x * blockDim.x + threadIdx.x;
    float ki = keys[i];
    int rank = 0;
    for (int j = 0; j < M_ROWS; ++j) {
        float kj = keys[j];
        rank += (kj < ki) || (kj == ki && j < i);  // stable rank
    }
    perm[rank] = i;
}

// ---------------- gather sorted rows + L2-normalize (drop time col) ----------------
__global__ __launch_bounds__(128) void norm_kernel(const float* __restrict__ a, const float* __restrict__ b,
                                                   const int* __restrict__ permA, const int* __restrict__ permB,
                                                   float* __restrict__ Ahat, float* __restrict__ Bhat) {
    const float* src = blockIdx.y ? b : a;
    const int* perm = blockIdx.y ? permB : permA;
    float* dst = blockIdx.y ? Bhat : Ahat;
    int r = blockIdx.x;
    int row = perm[r];
    const float* p = src + (size_t)row * IN_STRIDE;
    int tid = threadIdx.x;
    float v0 = p[tid], v1 = p[tid + 128], v2 = p[tid + 256], v3 = p[tid + 384];
    float ss = v0 * v0 + v1 * v1 + v2 * v2 + v3 * v3;
    #pragma unroll
    for (int off = 32; off > 0; off >>= 1) ss += __shfl_down(ss, off);
    __shared__ float red[2];
    if ((tid & 63) == 0) red[tid >> 6] = ss;
    __syncthreads();
    float inv = 1.0f / sqrtf(red[0] + red[1] + 1e-10f);
    float* q = dst + (size_t)r * DIMS;
    q[tid] = v0 * inv; q[tid + 128] = v1 * inv; q[tid + 256] = v2 * inv; q[tid + 384] = v3 * inv;
}

// ---------------- GEMM: Q[i][n] = exp(-1 - dot(Ahat[i], Bhat[n])) = exp(cost-2) ----------------
__global__ __launch_bounds__(256) void gemm_kernel(const float* __restrict__ A, const float* __restrict__ B,
                                                   float* __restrict__ Q) {
    __shared__ float As[16][68];
    __shared__ float Bs[16][68];
    int tid = threadIdx.x;
    int tx = tid & 15, ty = tid >> 4;
    int row0 = blockIdx.y * 64;
    int col0 = blockIdx.x * 64;
    int lrow = tid >> 2;          // 0..63
    int lk = (tid & 3) * 4;       // 0,4,8,12
    const float* ap = A + (size_t)(row0 + lrow) * DIMS + lk;
    const float* bp = B + (size_t)(col0 + lrow) * DIMS + lk;
    float acc[4][4] = {};
    for (int k0 = 0; k0 < DIMS; k0 += 16) {
        float4 av = *(const float4*)ap; ap += 16;
        float4 bv = *(const float4*)bp; bp += 16;
        __syncthreads();
        As[lk + 0][lrow] = av.x; As[lk + 1][lrow] = av.y; As[lk + 2][lrow] = av.z; As[lk + 3][lrow] = av.w;
        Bs[lk + 0][lrow] = bv.x; Bs[lk + 1][lrow] = bv.y; Bs[lk + 2][lrow] = bv.z; Bs[lk + 3][lrow] = bv.w;
        __syncthreads();
        #pragma unroll
        for (int k = 0; k < 16; ++k) {
            float4 a4 = *(const float4*)&As[k][ty * 4];
            float4 b4 = *(const float4*)&Bs[k][tx * 4];
            float aa[4] = {a4.x, a4.y, a4.z, a4.w};
            float bb[4] = {b4.x, b4.y, b4.z, b4.w};
            #pragma unroll
            for (int u = 0; u < 4; ++u)
                #pragma unroll
                for (int v = 0; v < 4; ++v)
                    acc[u][v] += aa[u] * bb[v];
        }
    }
    #pragma unroll
    for (int u = 0; u < 4; ++u) {
        float4 o;
        o.x = __expf(-1.0f - acc[u][0]);
        o.y = __expf(-1.0f - acc[u][1]);
        o.z = __expf(-1.0f - acc[u][2]);
        o.w = __expf(-1.0f - acc[u][3]);
        *(float4*)&Q[(size_t)(row0 + ty * 4 + u) * N_COLS + col0 + tx * 4] = o;
    }
}

// ---------------- per-row softmax denom -> rs2 = log2e/(gamma*denom) ----------------
__global__ __launch_bounds__(256) void rowstat_kernel(const float* __restrict__ Q,
                                                      float* __restrict__ rowscale) {
    int i = blockIdx.x;
    const float* q = Q + (size_t)i * N_COLS;
    int tid = threadIdx.x;
    float4 x = *(const float4*)(q + tid * 4);
    float4 y = *(const float4*)(q + 1024 + tid * 4);
    float s = x.x + x.y + x.z + x.w + y.x + y.y + y.z + y.w;
    #pragma unroll
    for (int off = 32; off > 0; off >>= 1) s += __shfl_down(s, off);
    __shared__ float red[4];
    if ((tid & 63) == 0) red[tid >> 6] = s;
    __syncthreads();
    if (tid == 0) {
        float denom = 2049.0f + red[0] + red[1] + red[2] + red[3];
        rowscale[i] = (LOG2E / GAMMA) / denom;
    }
}

// ---------------- LG2T[col][row] = log2(We_row + Wo_row[col]), tiled transpose ----------
// Column-major layout so a DP lane's 16 band rows are one contiguous 64B line.
__global__ __launch_bounds__(256) void lgt_kernel(const float* __restrict__ Q,
                                                  const float* __restrict__ rowscale,
                                                  float* __restrict__ LG2T) {
    __shared__ float tile[64][65];
    const int row0 = blockIdx.y * 64;
    const int col0 = blockIdx.x * 64;
    const int t = threadIdx.x;
    const int c4 = (t & 15) * 4;
    const int r  = t >> 4;           // 0..15
    #pragma unroll
    for (int rr = 0; rr < 64; rr += 16) {
        int row = row0 + rr + r;
        float rs = rowscale[row];
        float4 v = *(const float4*)(Q + (size_t)row * N_COLS + col0 + c4);
        float e = fexp2(-rs);
        tile[c4 + 0][rr + r] = flog2(e + fexp2(-rs * v.x));
        tile[c4 + 1][rr + r] = flog2(e + fexp2(-rs * v.y));
        tile[c4 + 2][rr + r] = flog2(e + fexp2(-rs * v.z));
        tile[c4 + 3][rr + r] = flog2(e + fexp2(-rs * v.w));
    }
    __syncthreads();
    #pragma unroll
    for (int cc = 0; cc < 64; cc += 16) {
        int col = cc + r;
        float4 o;
        o.x = tile[col][c4 + 0];
        o.y = tile[col][c4 + 1];
        o.z = tile[col][c4 + 2];
        o.w = tile[col][c4 + 3];
        *(float4*)(LG2T + (size_t)(col0 + col) * M_ROWS + row0 + c4) = o;
    }
}

// ---------------- (m,s) pair arithmetic: value = m + log2(s) ----------------
struct Pair { float m, s; };
constexpr float ID_M = -1e30f;

__device__ __forceinline__ Pair pcomb(Pair a, Pair b) {
    float e = fexp2(-fabsf(a.m - b.m));
    bool c = a.m >= b.m;
    Pair r;
    r.m = c ? a.m : b.m;
    r.s = c ? fmaf(b.s, e, a.s) : fmaf(a.s, e, b.s);
    return r;
}
__device__ __forceinline__ void renorm(float& m, float& s) {
    int bits = __float_as_int(s);
    int ex = ((bits >> 23) & 255) - 127;
    m += (float)ex;
    s = __int_as_float(bits - (ex << 23));
}

// DPP mov with explicit old-value (bound_ctrl=false: invalid/masked lanes keep old)
template<int CTRL, int ROWM>
__device__ __forceinline__ float fdpp(float oldv, float src) {
    return __int_as_float(__builtin_amdgcn_update_dpp(
        __float_as_int(oldv), __float_as_int(src), CTRL, ROWM, 0xF, false));
}
// wave64 inclusive MAX-scan
__device__ __forceinline__ float wave_max_scan(float m) {
    m = fmaxf(m, fdpp<0x111,0xF>(ID_M, m));
    m = fmaxf(m, fdpp<0x112,0xF>(ID_M, m));
    m = fmaxf(m, fdpp<0x114,0xF>(ID_M, m));
    m = fmaxf(m, fdpp<0x118,0xF>(ID_M, m));
    m = fmaxf(m, fdpp<0x142,0xA>(ID_M, m));
    m = fmaxf(m, fdpp<0x143,0xC>(ID_M, m));
    return m;
}
// wave64 inclusive AFFINE scan: S[n] = S[n-1]*a[n] + z[n]; mul+fma only.
__device__ __forceinline__ void affine_scan(float& A, float& S) {
    { float Ap = fdpp<0x111,0xF>(1.0f, A), Sp = fdpp<0x111,0xF>(0.0f, S); S = fmaf(Sp, A, S); A = A * Ap; }
    { float Ap = fdpp<0x112,0xF>(1.0f, A), Sp = fdpp<0x112,0xF>(0.0f, S); S = fmaf(Sp, A, S); A = A * Ap; }
    { float Ap = fdpp<0x114,0xF>(1.0f, A), Sp = fdpp<0x114,0xF>(0.0f, S); S = fmaf(Sp, A, S); A = A * Ap; }
    { float Ap = fdpp<0x118,0xF>(1.0f, A), Sp = fdpp<0x118,0xF>(0.0f, S); S = fmaf(Sp, A, S); A = A * Ap; }
    { float Ap = fdpp<0x142,0xA>(1.0f, A), Sp = fdpp<0x142,0xA>(0.0f, S); S = fmaf(Sp, A, S); A = A * Ap; }
    { float Ap = fdpp<0x143,0xC>(1.0f, A), Sp = fdpp<0x143,0xC>(0.0f, S); S = fmaf(Sp, A, S); A = A * Ap; }
}
// lane (n-1) value, crossing 16-lane DPP row boundaries
__device__ __forceinline__ float lane_prev(float x, int lane, float idv) {
    float am = fdpp<0x111,0xF>(idv, x);
    float bm = fdpp<0x142,0xA>(idv, x);
    float cm = fdpp<0x143,0x4>(idv, x);
    bool s15 = (lane == 16) || (lane == 48);
    bool s31 = (lane == 32);
    return s15 ? bm : (s31 ? cm : am);
}

// one DP row; LGV/RSV must be STATIC float4-component expressions (no arrays ->
// no SROA failure -> no scratch; rounds 9-12 lost ~700 cy/row to scratch rings)
#define DP_ROW(U, LGV, RSV)                                                      \
    {                                                                            \
        const int row = base + (U);                                              \
        float lwe = -(RSV);                                                      \
        float g = mP + (LGV);                                                    \
        float M = wave_max_scan(g);                                              \
        float Mp = lane_prev(M, lane, ID_M);                                     \
        float aa = (lane == 0) ? 1.0f : fexp2(Mp - M);                           \
        float zz = sP * fexp2(g - M);                                            \
        float A = aa, S = zz;                                                    \
        affine_scan(A, S);                                                       \
        float Sp_ = lane_prev(S, lane, 0.0f);                                    \
        Pair ex{(lane == 0) ? ID_M : Mp, (lane == 0) ? 0.f : Sp_};               \
        Pair cin{ID_M, 0.f};                                                     \
        if (s > 0) {                                                             \
            cin.m = __int_as_float(__builtin_amdgcn_readlane(pkLo, (U)));        \
            cin.s = __int_as_float(__builtin_amdgcn_readlane(pkHi, (U)));        \
        }                                                                        \
        Pair v{M, S};                                                            \
        if (s < DP_BLOCKS - 1) {                                                 \
            if (lane == 63) {                                                    \
                Pair tot = pcomb(cin, v);                                        \
                unsigned long long po =                                          \
                    ((unsigned long long)__float_as_uint(tot.s) << 32)           \
                    | (unsigned long long)__float_as_uint(tot.m);                \
                __hip_atomic_store(pub + row, po, __ATOMIC_RELAXED,              \
                                   __HIP_MEMORY_SCOPE_AGENT);                    \
            }                                                                    \
        } else {                                                                 \
            Pair tot = pcomb(cin, v);                                            \
            Pair hh = pcomb(tot, Pair{mH + lwe, sH});                            \
            mH = hh.m; sH = hh.s;                                                \
            renorm(mH, sH);                                                      \
        }                                                                        \
        float dm = mP + lwe;                                                     \
        float m3 = fmaxf(fmaxf(cin.m, ex.m), dm);                                \
        float s3 = cin.s * fexp2(cin.m - m3)                                     \
                 + ex.s  * fexp2(ex.m  - m3)                                     \
                 + sP    * fexp2(dm    - m3);                                    \
        mP = m3; sP = s3;                                                        \
        renorm(mP, sP);                                                          \
    }

// ---------------- pipelined multi-block DP, banded carries, register band data ----
__global__ __launch_bounds__(64) void dp_kernel(const float* __restrict__ LG2T,
                                                const float* __restrict__ Rs,
                                                unsigned long long* __restrict__ carry,
                                                float* __restrict__ out) {
    const int s = ((blockIdx.x & 7) << 2) | (blockIdx.x >> 3);  // XCD-aware stripe id
    const int lane = threadIdx.x;
    const float* lcol = LG2T + (size_t)(s * DP_COLS + lane) * M_ROWS;
    unsigned long long* pub = carry + (size_t)s * M_ROWS;
    const unsigned long long* sub = carry + (size_t)(s - 1) * M_ROWS;

    float mP = 0.f, sP = 1.f;      // virtual row -1: P = log2(1)
    float mH = 0.f, sH = 1.f;      // stripe 31, lane 63 only

    float4 lq0 = *(const float4*)(lcol + 0);
    float4 lq1 = *(const float4*)(lcol + 4);
    float4 lq2 = *(const float4*)(lcol + 8);
    float4 lq3 = *(const float4*)(lcol + 12);
    float4 rv0 = *(const float4*)(Rs + 0);
    float4 rv1 = *(const float4*)(Rs + 4);
    float4 rv2 = *(const float4*)(Rs + 8);
    float4 rv3 = *(const float4*)(Rs + 12);

    for (int base = 0; base < M_ROWS; base += BAND) {
        // prefetch next band first (independent; completes during rows below)
        float4 nl0{}, nl1{}, nl2{}, nl3{}, nv0{}, nv1{}, nv2{}, nv3{};
        if (base + BAND < M_ROWS) {
            nl0 = *(const float4*)(lcol + base + BAND);
            nl1 = *(const float4*)(lcol + base + BAND + 4);
            nl2 = *(const float4*)(lcol + base + BAND + 8);
            nl3 = *(const float4*)(lcol + base + BAND + 12);
            nv0 = *(const float4*)(Rs + base + BAND);
            nv1 = *(const float4*)(Rs + base + BAND + 4);
            nv2 = *(const float4*)(Rs + base + BAND + 8);
            nv3 = *(const float4*)(Rs + base + BAND + 12);
        }
        // band poll: lane u<16 spins on its own row's carry
        unsigned long long pk = 1ull;
        if (s > 0 && lane < BAND) {
            const unsigned long long* p = sub + base + lane;
            do {
                pk = __hip_atomic_load(p, __ATOMIC_RELAXED, __HIP_MEMORY_SCOPE_AGENT);
            } while (pk == 0ull);
        }
        int pkLo = (int)(unsigned)(pk & 0xFFFFFFFFull);
        int pkHi = (int)(unsigned)(pk >> 32);

        DP_ROW(0,  lq0.x, rv0.x)
        DP_ROW(1,  lq0.y, rv0.y)
        DP_ROW(2,  lq0.z, rv0.z)
        DP_ROW(3,  lq0.w, rv0.w)
        DP_ROW(4,  lq1.x, rv1.x)
        DP_ROW(5,  lq1.y, rv1.y)
        DP_ROW(6,  lq1.z, rv1.z)
        DP_ROW(7,  lq1.w, rv1.w)
        DP_ROW(8,  lq2.x, rv2.x)
        DP_ROW(9,  lq2.y, rv2.y)
        DP_ROW(10, lq2.z, rv2.z)
        DP_ROW(11, lq2.w, rv2.w)
        DP_ROW(12, lq3.x, rv3.x)
        DP_ROW(13, lq3.y, rv3.y)
        DP_ROW(14, lq3.z, rv3.z)
        DP_ROW(15, lq3.w, rv3.w)

        lq0 = nl0; lq1 = nl1; lq2 = nl2; lq3 = nl3;
        rv0 = nv0; rv1 = nv1; rv2 = nv2; rv3 = nv3;
    }
    if (s == DP_BLOCKS - 1 && lane == 63)
        out[0] = -GAMMA * LN2 * (mH + flog2(sH));
}

extern "C" void kernel_launch(void* const* d_in, const int* in_sizes, int n_in,
                              void* d_out, int out_size, void* d_ws, size_t ws_size,
                              hipStream_t stream) {
    (void)in_sizes; (void)n_in; (void)out_size; (void)ws_size;
    const float* a = (const float*)d_in[0];
    const float* b = (const float*)d_in[1];
    float* out = (float*)d_out;
    char* ws = (char*)d_ws;
    float* Q        = (float*)(ws);                                    // 16 MB
    float* LG2T     = (float*)(ws + (size_t)16 * 1024 * 1024);         // 16 MB
    float* Ahat     = (float*)(ws + (size_t)32 * 1024 * 1024);         // 4 MB
    float* Bhat     = (float*)(ws + (size_t)36 * 1024 * 1024);         // 4 MB
    float* rowscale = (float*)(ws + (size_t)40 * 1024 * 1024);         // 8 KB
    int* permA      = (int*)(ws + (size_t)40 * 1024 * 1024 + 8192);    // 8 KB
    int* permB      = (int*)(ws + (size_t)40 * 1024 * 1024 + 16384);   // 8 KB
    unsigned long long* carry = (unsigned long long*)(ws + (size_t)41 * 1024 * 1024); // 512 KB

    hipMemsetAsync(carry, 0, (size_t)DP_BLOCKS * M_ROWS * sizeof(unsigned long long), stream);
    argsort_kernel<<<dim3(8, 2), 256, 0, stream>>>(a, b, permA, permB);
    norm_kernel<<<dim3(2048, 2), 128, 0, stream>>>(a, b, permA, permB, Ahat, Bhat);
    gemm_kernel<<<dim3(32, 32), 256, 0, stream>>>(Ahat, Bhat, Q);
    rowstat_kernel<<<2048, 256, 0, stream>>>(Q, rowscale);
    lgt_kernel<<<dim3(32, 32), 256, 0, stream>>>(Q, rowscale, LG2T);
    dp_kernel<<<DP_BLOCKS, DP_COLS, 0, stream>>>(LG2T, rowscale, carry, out);
}